// Round 1
// baseline (31781.387 us; speedup 1.0000x reference)
//
#include <hip/hip_runtime.h>
#include <math.h>

// Problem constants (AttnDecoderRNN): H=1024 hidden, V=16000 vocab, B=64 batch,
// L=256 enc len, T=128 decoder steps.
#define HH 1024
#define VV 16000
#define BB 64
#define LL 256
#define TT 128

// ---------------------------------------------------------------------------
// Workspace layout (floats):
//   H_all  [T][B][H]   : h_t for every step (feeds the big output GEMM)
//   xin    [B][2H]     : e | ctx   (input to comb GEMM)
//   x_acc  [B][H]      : comb GEMM accumulator (bias+relu applied by consumer)
//   gates  [B][4H]     : gates GEMM accumulator (i,f,g,o)
//   h_buf  [B][H], c_buf [B][H]
// ---------------------------------------------------------------------------

__device__ __forceinline__ float sigm(float x) { return 1.0f / (1.0f + expf(-x)); }

// ---- LSTM elementwise for step (t-1): consumes gates accumulator ----------
__device__ void lstm_apply(const float* __restrict__ gates_acc,
                           const float* __restrict__ b_ih,
                           const float* __restrict__ b_hh,
                           float* __restrict__ c_buf,
                           float* __restrict__ h_buf,
                           float* __restrict__ Hall_t,
                           float* h_s,     // optional LDS dest (this block's h)
                           int b, int tid, bool first_c)
{
    const int j = tid * 4;
    const float* gb = gates_acc + (size_t)b * 4 * HH;
    float4 gi = *(const float4*)(gb + j);
    float4 gf = *(const float4*)(gb + HH + j);
    float4 gg = *(const float4*)(gb + 2 * HH + j);
    float4 go = *(const float4*)(gb + 3 * HH + j);
    float4 bii = *(const float4*)(b_ih + j),          bhi = *(const float4*)(b_hh + j);
    float4 bif_ = *(const float4*)(b_ih + HH + j),    bhf = *(const float4*)(b_hh + HH + j);
    float4 big = *(const float4*)(b_ih + 2 * HH + j), bhg = *(const float4*)(b_hh + 2 * HH + j);
    float4 bio = *(const float4*)(b_ih + 3 * HH + j), bho = *(const float4*)(b_hh + 3 * HH + j);
    float4 co = first_c ? make_float4(0.f, 0.f, 0.f, 0.f)
                        : *(const float4*)(c_buf + (size_t)b * HH + j);
    float4 cn, hn;
#define DO_LSTM(X)                                        \
    {                                                     \
        float iv = sigm(gi.X + bii.X + bhi.X);            \
        float fv = sigm(gf.X + bif_.X + bhf.X);           \
        float gv = tanhf(gg.X + big.X + bhg.X);           \
        float ov = sigm(go.X + bio.X + bho.X);            \
        float c2 = fv * co.X + iv * gv;                   \
        cn.X = c2;                                        \
        hn.X = ov * tanhf(c2);                            \
    }
    DO_LSTM(x) DO_LSTM(y) DO_LSTM(z) DO_LSTM(w)
#undef DO_LSTM
    *(float4*)(c_buf + (size_t)b * HH + j) = cn;
    *(float4*)(h_buf + (size_t)b * HH + j) = hn;
    *(float4*)(Hall_t + (size_t)b * HH + j) = hn;
    if (h_s) *(float4*)(h_s + j) = hn;
}

// ---------------------------------------------------------------------------
// k_attn: one block per batch element b.
//  - LSTM for step t-1 (t>0), producing h_{t-1} into LDS + h_buf + H_all
//  - gather e = emb[tok]; write e into xin[b][0:H]
//  - scores[l] = <e|h , W_attn[l]> + b_attn[l]  (4 waves x 64 l each)
//  - softmax over l; ctx = sum_l aw[l]*enc[l,b,:]; write ctx to xin[b][H:2H]
//  - zeroes x_acc[b] for this step's comb accumulation
// ---------------------------------------------------------------------------
__global__ __launch_bounds__(256) void k_attn(
    const int* __restrict__ tok_all, const float* __restrict__ enc,
    const float* __restrict__ emb, const float* __restrict__ Wattn,
    const float* __restrict__ battn, const float* __restrict__ b_ih,
    const float* __restrict__ b_hh, float* __restrict__ Hall,
    float* __restrict__ xin, float* __restrict__ x_acc,
    const float* __restrict__ gates_acc, float* __restrict__ h_buf,
    float* __restrict__ c_buf, int t)
{
    const int b = blockIdx.x;
    const int tid = threadIdx.x;
    __shared__ float e_s[HH];
    __shared__ float h_s[HH];
    __shared__ float sc[LL];
    __shared__ float red[8];

    // zero this b's comb accumulator (consumed later this step)
    ((float4*)(x_acc + (size_t)b * HH))[tid] = make_float4(0.f, 0.f, 0.f, 0.f);

    // token (robust to int32 vs int64 device layout; values < 2^31)
    const int is64 = (tok_all[1] == 0 && tok_all[3] == 0 && tok_all[5] == 0 && tok_all[7] == 0);
    const int tok = is64 ? tok_all[2 * (b * TT + t)] : tok_all[b * TT + t];

    float4 ev = ((const float4*)(emb + (size_t)tok * HH))[tid];
    ((float4*)e_s)[tid] = ev;
    ((float4*)(xin + (size_t)b * 2 * HH))[tid] = ev;

    if (t == 0) {
        float4 hv = ((const float4*)(enc + (size_t)(LL - 1) * BB * HH + (size_t)b * HH))[tid];
        ((float4*)h_s)[tid] = hv;
        ((float4*)(h_buf + (size_t)b * HH))[tid] = hv;
    } else {
        lstm_apply(gates_acc, b_ih, b_hh, c_buf, h_buf,
                   Hall + (size_t)(t - 1) * BB * HH, h_s, b, tid, t == 1);
    }
    __syncthreads();

    // ---- scores: wave w handles l in [w*64, w*64+64) ----
    const int w = tid >> 6, lane = tid & 63;
    const float4* es4 = (const float4*)e_s;
    const float4* hs4 = (const float4*)h_s;
    for (int li = 0; li < 64; ++li) {
        const int l = w * 64 + li;
        const float4* wr = (const float4*)(Wattn + (size_t)l * 2 * HH);
        float a = 0.f;
#pragma unroll
        for (int it = 0; it < 4; ++it) {
            float4 wv = wr[it * 64 + lane];
            float4 xv = es4[it * 64 + lane];
            a += wv.x * xv.x + wv.y * xv.y + wv.z * xv.z + wv.w * xv.w;
        }
#pragma unroll
        for (int it = 0; it < 4; ++it) {
            float4 wv = wr[256 + it * 64 + lane];
            float4 xv = hs4[it * 64 + lane];
            a += wv.x * xv.x + wv.y * xv.y + wv.z * xv.z + wv.w * xv.w;
        }
#pragma unroll
        for (int o = 32; o > 0; o >>= 1) a += __shfl_down(a, o, 64);
        if (lane == 0) sc[l] = a + battn[l];
    }
    __syncthreads();

    // ---- softmax over sc[0..255] (one element per thread) ----
    const float sv = sc[tid];
    float m = sv;
#pragma unroll
    for (int o = 32; o > 0; o >>= 1) m = fmaxf(m, __shfl_down(m, o, 64));
    if (lane == 0) red[w] = m;
    __syncthreads();
    m = fmaxf(fmaxf(red[0], red[1]), fmaxf(red[2], red[3]));
    const float ex = expf(sv - m);
    float s = ex;
#pragma unroll
    for (int o = 32; o > 0; o >>= 1) s += __shfl_down(s, o, 64);
    if (lane == 0) red[4 + w] = s;
    __syncthreads();
    const float tot = red[4] + red[5] + red[6] + red[7];
    sc[tid] = ex / tot;
    __syncthreads();

    // ---- ctx[b][4*tid .. 4*tid+3] = sum_l aw[l] * enc[l][b][...] ----
    float4 ctx = make_float4(0.f, 0.f, 0.f, 0.f);
    const float4* ebase = (const float4*)(enc + (size_t)b * HH) + tid;
#pragma unroll 4
    for (int l = 0; l < LL; ++l) {
        const float a = sc[l];
        float4 e2 = ebase[(size_t)l * (BB * HH / 4)];
        ctx.x += a * e2.x; ctx.y += a * e2.y; ctx.z += a * e2.z; ctx.w += a * e2.w;
    }
    ((float4*)(xin + (size_t)b * 2 * HH + HH))[tid] = ctx;
}

// ---------------------------------------------------------------------------
// Shared fp32 GEMM tile core: C[64 x 64] partial over k-range, atomicAdd out.
// A is [64][lda] row-major; W is [N][ldw] row-major (so C = A @ W^T).
// If RELU_BIAS: A element (b,k) -> relu(A[b][k] + abias[k]).
// ---------------------------------------------------------------------------
template <bool RELU_BIAS>
__device__ void gemm64x64(const float* __restrict__ A, int lda,
                          const float* __restrict__ abias,
                          const float* __restrict__ Wm, int ldw,
                          int n0, int k0, int klen,
                          float* __restrict__ Cacc, int ldc)
{
    __shared__ float As[32][68];
    __shared__ float Ws[32][68];
    const int tid = threadIdx.x;
    const int ty = tid >> 4, tx = tid & 15;  // thread computes 4x4 at (ty*4, tx*4)
    const int q = tid & 7, r = tid >> 3;     // loader: float4 col q, row r(+32)
    float acc[4][4] = {};

    for (int kc = k0; kc < k0 + klen; kc += 32) {
#pragma unroll
        for (int rr = 0; rr < 2; ++rr) {
            const int row = r + rr * 32;
            float4 v = *(const float4*)(A + (size_t)row * lda + kc + q * 4);
            if (RELU_BIAS) {
                const float4 bv = *(const float4*)(abias + kc + q * 4);
                v.x = fmaxf(v.x + bv.x, 0.f);
                v.y = fmaxf(v.y + bv.y, 0.f);
                v.z = fmaxf(v.z + bv.z, 0.f);
                v.w = fmaxf(v.w + bv.w, 0.f);
            }
            As[q * 4 + 0][row] = v.x; As[q * 4 + 1][row] = v.y;
            As[q * 4 + 2][row] = v.z; As[q * 4 + 3][row] = v.w;
            float4 wv = *(const float4*)(Wm + (size_t)(n0 + row) * ldw + kc + q * 4);
            Ws[q * 4 + 0][row] = wv.x; Ws[q * 4 + 1][row] = wv.y;
            Ws[q * 4 + 2][row] = wv.z; Ws[q * 4 + 3][row] = wv.w;
        }
        __syncthreads();
#pragma unroll
        for (int k = 0; k < 32; ++k) {
            const float4 a = *(const float4*)&As[k][ty * 4];
            const float4 wv = *(const float4*)&Ws[k][tx * 4];
            const float av[4] = {a.x, a.y, a.z, a.w};
            const float bv[4] = {wv.x, wv.y, wv.z, wv.w};
#pragma unroll
            for (int i = 0; i < 4; ++i)
#pragma unroll
                for (int j = 0; j < 4; ++j) acc[i][j] += av[i] * bv[j];
        }
        __syncthreads();
    }
#pragma unroll
    for (int i = 0; i < 4; ++i)
#pragma unroll
        for (int j = 0; j < 4; ++j)
            atomicAdd(Cacc + (size_t)(ty * 4 + i) * ldc + n0 + tx * 4 + j, acc[i][j]);
}

// comb: x_acc += xin @ W_comb^T ; grid (16 n-tiles, 8 k-splits). Also zeroes gates_acc.
__global__ __launch_bounds__(256) void k_comb(const float* __restrict__ xin,
                                              const float* __restrict__ Wcomb,
                                              float* __restrict__ x_acc,
                                              float* __restrict__ gates_acc)
{
    const int blin = blockIdx.y * gridDim.x + blockIdx.x;  // 0..127
    float4* gz = (float4*)gates_acc;
    gz[blin * 512 + threadIdx.x] = make_float4(0.f, 0.f, 0.f, 0.f);
    gz[blin * 512 + 256 + threadIdx.x] = make_float4(0.f, 0.f, 0.f, 0.f);
    gemm64x64<false>(xin, 2 * HH, nullptr, Wcomb, 2 * HH,
                     blockIdx.x * 64, blockIdx.y * 256, 256, x_acc, HH);
}

// gates: gates_acc += relu(x_acc+b_comb) @ W_ih^T + h @ W_hh^T
// grid (64 n-tiles, 4 k-splits of 512 over concat-K 2048)
__global__ __launch_bounds__(256) void k_gates(const float* __restrict__ x_acc,
                                               const float* __restrict__ h_buf,
                                               const float* __restrict__ b_comb,
                                               const float* __restrict__ W_ih,
                                               const float* __restrict__ W_hh,
                                               float* __restrict__ gates_acc)
{
    const int n0 = blockIdx.x * 64;
    const int k0 = blockIdx.y * 512;
    if (k0 < HH)
        gemm64x64<true>(x_acc, HH, b_comb, W_ih, HH, n0, k0, 512, gates_acc, 4 * HH);
    else
        gemm64x64<false>(h_buf, HH, nullptr, W_hh, HH, n0, k0 - HH, 512, gates_acc, 4 * HH);
}

// final LSTM (step T-1) -> H_all[T-1]
__global__ __launch_bounds__(256) void k_lstm_fin(const float* __restrict__ gates_acc,
                                                  const float* __restrict__ b_ih,
                                                  const float* __restrict__ b_hh,
                                                  float* __restrict__ c_buf,
                                                  float* __restrict__ h_buf,
                                                  float* __restrict__ Hall)
{
    lstm_apply(gates_acc, b_ih, b_hh, c_buf, h_buf,
               Hall + (size_t)(TT - 1) * BB * HH, nullptr, blockIdx.x, threadIdx.x, false);
}

// ---------------------------------------------------------------------------
// k_out: out[t,b,v] = logits - LSE over b (log_softmax over BATCH axis).
// Block: (n-tile of 128 vocab cols, one t). Tile 64x128, K=1024 fp32.
// b_out cancels exactly in log-softmax over batch -> skipped.
// ---------------------------------------------------------------------------
__global__ __launch_bounds__(256) void k_out(const float* __restrict__ Hall,
                                             const float* __restrict__ Wout,
                                             float* __restrict__ out)
{
    const int t = blockIdx.y;
    const int n0 = blockIdx.x * 128;
    const float* A = Hall + (size_t)t * BB * HH;
    __shared__ float As[32][68];
    __shared__ float Ws[32][132];
    __shared__ float Cs[64][129];
    __shared__ float lse_s[128];
    const int tid = threadIdx.x;
    const int ty = tid >> 4, tx = tid & 15;  // thread tile 4 rows x 8 cols
    const int q = tid & 7, r = tid >> 3;
    float acc[4][8] = {};

    for (int kc = 0; kc < HH; kc += 32) {
#pragma unroll
        for (int rr = 0; rr < 2; ++rr) {
            const int row = r + rr * 32;
            float4 v = *(const float4*)(A + (size_t)row * HH + kc + q * 4);
            As[q * 4 + 0][row] = v.x; As[q * 4 + 1][row] = v.y;
            As[q * 4 + 2][row] = v.z; As[q * 4 + 3][row] = v.w;
        }
#pragma unroll
        for (int rr = 0; rr < 4; ++rr) {
            const int row = r + rr * 32;
            float4 v = *(const float4*)(Wout + (size_t)(n0 + row) * HH + kc + q * 4);
            Ws[q * 4 + 0][row] = v.x; Ws[q * 4 + 1][row] = v.y;
            Ws[q * 4 + 2][row] = v.z; Ws[q * 4 + 3][row] = v.w;
        }
        __syncthreads();
#pragma unroll
        for (int k = 0; k < 32; ++k) {
            const float4 a = *(const float4*)&As[k][ty * 4];
            const float4 w0 = *(const float4*)&Ws[k][tx * 8];
            const float4 w1 = *(const float4*)&Ws[k][tx * 8 + 4];
            const float av[4] = {a.x, a.y, a.z, a.w};
            const float bv[8] = {w0.x, w0.y, w0.z, w0.w, w1.x, w1.y, w1.z, w1.w};
#pragma unroll
            for (int i = 0; i < 4; ++i)
#pragma unroll
                for (int j = 0; j < 8; ++j) acc[i][j] += av[i] * bv[j];
        }
        __syncthreads();
    }
#pragma unroll
    for (int i = 0; i < 4; ++i)
#pragma unroll
        for (int j = 0; j < 8; ++j) Cs[ty * 4 + i][tx * 8 + j] = acc[i][j];
    __syncthreads();

    if (tid < 128) {
        float m = -1e30f;
        for (int b = 0; b < 64; ++b) m = fmaxf(m, Cs[b][tid]);
        float s = 0.f;
        for (int b = 0; b < 64; ++b) s += expf(Cs[b][tid] - m);
        lse_s[tid] = m + logf(s);
    }
    __syncthreads();

    const int col = tid & 127, bh = tid >> 7;
    float* outp = out + (size_t)t * BB * VV + n0 + col;
    for (int b = bh; b < 64; b += 2)
        outp[(size_t)b * VV] = Cs[b][col] - lse_s[col];
}

// ---------------------------------------------------------------------------
extern "C" void kernel_launch(void* const* d_in, const int* in_sizes, int n_in,
                              void* d_out, int out_size, void* d_ws, size_t ws_size,
                              hipStream_t stream)
{
    const int* tok = (const int*)d_in[0];
    const float* enc = (const float*)d_in[1];
    const float* emb = (const float*)d_in[2];
    const float* W_attn = (const float*)d_in[3];
    const float* b_attn = (const float*)d_in[4];
    const float* W_comb = (const float*)d_in[5];
    const float* b_comb = (const float*)d_in[6];
    const float* W_ih = (const float*)d_in[7];
    const float* W_hh = (const float*)d_in[8];
    const float* b_ih = (const float*)d_in[9];
    const float* b_hh = (const float*)d_in[10];
    const float* W_out = (const float*)d_in[11];
    // d_in[12] = b_out: constant over batch -> cancels in log_softmax(axis=batch)
    float* out = (float*)d_out;
    float* ws = (float*)d_ws;

    const size_t n_Hall = (size_t)TT * BB * HH;        // 8388608
    const size_t n_xin = (size_t)BB * 2 * HH;          // 131072
    const size_t n_xacc = (size_t)BB * HH;             // 65536
    const size_t n_gates = (size_t)BB * 4 * HH;        // 262144
    const size_t needed = (n_Hall + n_xin + n_xacc + n_gates + 2 * (size_t)BB * HH) * 4;
    if (ws_size < needed) return;  // would corrupt; bail (visible as incorrect)

    float* H_all = ws;
    float* xin = H_all + n_Hall;
    float* x_acc = xin + n_xin;
    float* gates_acc = x_acc + n_xacc;
    float* h_buf = gates_acc + n_gates;
    float* c_buf = h_buf + (size_t)BB * HH;

    for (int t = 0; t < TT; ++t) {
        k_attn<<<BB, 256, 0, stream>>>(tok, enc, emb, W_attn, b_attn, b_ih, b_hh,
                                       H_all, xin, x_acc, gates_acc, h_buf, c_buf, t);
        k_comb<<<dim3(16, 8), 256, 0, stream>>>(xin, W_comb, x_acc, gates_acc);
        k_gates<<<dim3(64, 4), 256, 0, stream>>>(x_acc, h_buf, b_comb, W_ih, W_hh,
                                                 gates_acc);
    }
    k_lstm_fin<<<BB, 256, 0, stream>>>(gates_acc, b_ih, b_hh, c_buf, h_buf, H_all);
    k_out<<<dim3(125, 128), 256, 0, stream>>>(H_all, W_out, out);
}